// Round 15
// baseline (96.443 us; speedup 1.0000x reference)
//
#include <hip/hip_runtime.h>
#include <hip/hip_bf16.h>
#include <math.h>

#define NSEQ 26
#define NSUP 25
#define LSEQ 46
#define DJ 90
#define H1 180
#define DIN 256
#define TT 1035
#define TTP 1056     // 33*32 keys padded
#define DOUT 128
#define WAY 5
#define SHOT 5
#define NPB 130      // proto/logits blocks per class: ceil(33120/256)
#define PROWS 4      // proj rows per block (1196 = 4*299)
#define SQRT_SCALE 0.29730177875068026f   // (1/sqrt(128))^0.5 folded into K (Q and K both)

typedef __attribute__((ext_vector_type(8))) short short8;
typedef __attribute__((ext_vector_type(4))) float f32x4;

__device__ __forceinline__ ushort f2bf(float x) {
    __hip_bfloat16 h = __float2bfloat16(x);
    return *reinterpret_cast<ushort*>(&h);
}

// ---------------- kernel 1: MLP (two relu layers) + positional encoding ----------------
__global__ void mlp_pe_kernel(const float* __restrict__ ss, const float* __restrict__ qsk,
                              const float* __restrict__ w1, const float* __restrict__ b1,
                              const float* __restrict__ w2, const float* __restrict__ b2,
                              float* __restrict__ feat) {
    __shared__ float xs[DJ];
    __shared__ float hs[H1];
    int r = blockIdx.x;
    int seq = r / LSEQ, l = r % LSEQ;
    const float* x = (seq < NSUP) ? (ss + (size_t)(seq * LSEQ + l) * DJ)
                                  : (qsk + (size_t)l * DJ);
    int tid = threadIdx.x;
    if (tid < DJ) xs[tid] = x[tid];
    __syncthreads();
    if (tid < H1) {
        float a = b1[tid];
        for (int k = 0; k < DJ; ++k) a += xs[k] * w1[k * H1 + tid];
        hs[tid] = fmaxf(a, 0.f);
    }
    __syncthreads();
    int d = tid;  // 0..255
    float a = b2[d];
    for (int k = 0; k < H1; ++k) a += hs[k] * w2[k * DIN + d];
    a = fmaxf(a, 0.f);
    int p2 = d & ~1;
    float freq = expf((float)p2 * (-9.210340371976184f / 256.0f));
    float ang = (float)l * freq;
    a += ((d & 1) ? cosf(ang) : sinf(ang)) * 0.1f;
    feat[(size_t)r * DIN + d] = a;
}

// ---------------- kernel 2: half projections, 4 rows/block (weight reuse in-block) ----------------
__global__ __launch_bounds__(256) void proj_kernel(
        const float* __restrict__ feat,
        const float* __restrict__ kw, const float* __restrict__ vw,
        float* __restrict__ kp1, float* __restrict__ kp2,
        float* __restrict__ vp1, float* __restrict__ vp2) {
    __shared__ float fs[PROWS][DIN];
    int r0 = blockIdx.x * PROWS;
    int tid = threadIdx.x;
    int d = tid & 127, h = tid >> 7;   // h=0: kw pair, h=1: vw pair
    #pragma unroll
    for (int rr = 0; rr < PROWS; ++rr)
        fs[rr][tid] = feat[(size_t)(r0 + rr) * DIN + tid];
    __syncthreads();
    const float* W = h ? vw : kw;
    float at[PROWS] = {0.f, 0.f, 0.f, 0.f};
    float ab[PROWS] = {0.f, 0.f, 0.f, 0.f};
    for (int k = 0; k < DIN; ++k) {
        float wt = W[k * DOUT + d];
        float wb = W[(k + DIN) * DOUT + d];
        #pragma unroll
        for (int rr = 0; rr < PROWS; ++rr) {
            float f = fs[rr][k];
            at[rr] += f * wt;
            ab[rr] += f * wb;
        }
    }
    #pragma unroll
    for (int rr = 0; rr < PROWS; ++rr) {
        size_t o = (size_t)(r0 + rr) * DOUT + d;
        if (h == 0) { kp1[o] = at[rr]; kp2[o] = ab[rr]; }
        else        { vp1[o] = at[rr]; vp2[o] = ab[rr]; }
    }
}

// ---------------- kernel 3: tuple gather + bias + LayerNorm, block per (seq, key-tile) ----------------
__global__ __launch_bounds__(256) void kv_kernel(
        const float* __restrict__ kp1, const float* __restrict__ kp2,
        const float* __restrict__ vp1, const float* __restrict__ vp2,
        const float* __restrict__ kb, const float* __restrict__ vb,
        const float* __restrict__ lg, const float* __restrict__ lb,
        ushort* __restrict__ Qbf, ushort* __restrict__ Kbf2,
        ushort* __restrict__ Vbf2, float* __restrict__ Vq) {
    int s = blockIdx.x / 33, kt = blockIdx.x % 33;
    int tid = threadIdx.x, wid = tid >> 6, lane = tid & 63;
    int lgrp = lane >> 4, dl = lane & 15;
    int d0 = dl * 8;
    int kc = d0 >> 5, gk = (d0 >> 3) & 3;

    #pragma unroll
    for (int pp = 0; pp < 2; ++pp) {
        int jq = pp * 16 + wid * 4 + lgrp;      // tuple within tile, 0..31
        int t = kt * 32 + jq;
        bool valid = t < TT;
        float kv8[8], vv8[8];
        #pragma unroll
        for (int e = 0; e < 8; ++e) { kv8[e] = 0.f; vv8[e] = 0.f; }
        if (valid) {
            int i = (int)((91.0f - sqrtf((float)(8281 - 8 * t))) * 0.5f);
            while (i > 0 && t < i * (91 - i) / 2) --i;
            while (i < 44 && t >= (i + 1) * (90 - i) / 2) ++i;
            int j = i + 1 + (t - i * (91 - i) / 2);
            const float* ki = kp1 + (size_t)(s * LSEQ + i) * DOUT + d0;
            const float* kj = kp2 + (size_t)(s * LSEQ + j) * DOUT + d0;
            const float* vi = vp1 + (size_t)(s * LSEQ + i) * DOUT + d0;
            const float* vj = vp2 + (size_t)(s * LSEQ + j) * DOUT + d0;
            #pragma unroll
            for (int e = 0; e < 8; ++e) {
                kv8[e] = ki[e] + kj[e] + kb[d0 + e];
                vv8[e] = vi[e] + vj[e] + vb[d0 + e];
            }
        }
        float sum = 0.f, sq = 0.f;
        #pragma unroll
        for (int e = 0; e < 8; ++e) { sum += kv8[e]; sq += kv8[e] * kv8[e]; }
        sum += __shfl_xor(sum, 1); sq += __shfl_xor(sq, 1);
        sum += __shfl_xor(sum, 2); sq += __shfl_xor(sq, 2);
        sum += __shfl_xor(sum, 4); sq += __shfl_xor(sq, 4);
        sum += __shfl_xor(sum, 8); sq += __shfl_xor(sq, 8);
        float m = sum * (1.f / DOUT);
        float var = sq * (1.f / DOUT) - m * m;
        float rs = rsqrtf(var + 1e-5f);
        short8 kn8;
        #pragma unroll
        for (int e = 0; e < 8; ++e) {
            float kn = valid ? ((kv8[e] - m) * rs * lg[d0 + e] + lb[d0 + e]) * SQRT_SCALE : 0.f;
            kn8[e] = (short)f2bf(kn);
        }
        if (s < NSUP) {
            int pos = (jq & 4) ? (16 + ((jq >> 3) << 2) + (jq & 3))
                               : (((jq >> 3) << 2) + (jq & 3));
            ushort* Ktile = Kbf2 + ((size_t)s * 33 + kt) * 4096;
            *(short8*)(Ktile + (size_t)((kc * 2 + (pos >> 4)) * 64 + gk * 16 + (pos & 15)) * 8) = kn8;
            ushort* Vtile = Vbf2 + ((size_t)s * 33 + kt) * 4096;
            int gv = jq >> 3, ev = jq & 7;
            #pragma unroll
            for (int e = 0; e < 8; ++e) {
                int d = d0 + e, db = d >> 4, r16v = d & 15;
                Vtile[(size_t)(db * 64 + gv * 16 + r16v) * 8 + ev] = valid ? f2bf(vv8[e]) : (ushort)0;
            }
        } else {
            int qt = t >> 4, r16q = t & 15;
            *(short8*)(Qbf + (size_t)qt * 2048 + (size_t)(kc * 64 + gk * 16 + r16q) * 8) = kn8;
            if (valid) {
                float* vq = Vq + (size_t)t * DOUT + d0;
                #pragma unroll
                for (int e = 0; e < 8; ++e) vq[e] = vv8[e];
            }
        }
    }
}

// ---------------- kernel 4: MFMA flash attention, 2 q-tiles/wave + 2-way split-K ----------------
// 450 blocks = 25 pairs x 9 q-groups x 2 k-splits. Block = 4 waves x 2 q-tiles
// (128 q rows); each k-split covers 17/16 key-tiles. K+V (16KB/tile) staged via
// global_load_lds, ONE barrier/tile. Each ds_read fragment feeds 4 MFMAs
// (2 q-tiles x 2 uses) -> LDS-read : MFMA = 192 : 320 cyc. Fixed-max softmax
// => split-K combine is a PLAIN SUM, folded into proto (writes unnormalized
// Opart + lpart). P in-register (permuted-K).
__global__ __launch_bounds__(256) void attn_mfma_kernel(
        const ushort* __restrict__ Qbf, const ushort* __restrict__ Kbf2,
        const ushort* __restrict__ Vbf2, float* __restrict__ Opart,
        float* __restrict__ lpart) {
    __shared__ __align__(16) ushort Kl[2][4096];
    __shared__ __align__(16) ushort Vl[2][4096];

    // bijective XCD-chunk swizzle (nwg=450, nwg%8=2)
    const int nwg = 450;
    int orig = blockIdx.x;
    int cq = nwg >> 3, cr = nwg & 7;           // 56, 2
    int xcd = orig & 7, sub = orig >> 3;
    int wg = (xcd < cr ? xcd * (cq + 1) : cr * (cq + 1) + (xcd - cr) * cq) + sub;
    int p = wg / 18;
    int rem = wg - p * 18;
    int ks = rem / 9;
    int qg = rem - ks * 9;

    int tid = threadIdx.x, wid = tid >> 6, lane = tid & 63;
    int g = lane >> 4, r16 = lane & 15;
    int qtA = qg * 8 + wid * 2, qtB = qtA + 1;   // 0..71 (>=66 masked)

    const short8 z8 = (short8){0, 0, 0, 0, 0, 0, 0, 0};
    short8 qfA[4], qfB[4];
    {
        const ushort* QbA = Qbf + (size_t)qtA * 2048;
        const ushort* QbB = Qbf + (size_t)qtB * 2048;
        bool okA = qtA < 66, okB = qtB < 66;
        #pragma unroll
        for (int kc = 0; kc < 4; ++kc) {
            qfA[kc] = okA ? *(const short8*)(QbA + (kc * 64 + lane) * 8) : z8;
            qfB[kc] = okB ? *(const short8*)(QbB + (kc * 64 + lane) * 8) : z8;
        }
    }

    int jt0 = ks ? 17 : 0;
    int ntl = ks ? 16 : 17;
    // staging split: wave0 K[0:2KB), wave1 K[2KB:4KB), wave2 V[0:2KB), wave3 V[2KB:)
    const ushort* gsrc = ((wid < 2) ? Kbf2 : Vbf2) + (size_t)p * 33 * 4096
                       + (size_t)jt0 * 4096 + (size_t)(wid & 1) * 2048;
    ushort* l0 = ((wid < 2) ? &Kl[0][0] : &Vl[0][0]) + (wid & 1) * 2048;
    ushort* l1 = ((wid < 2) ? &Kl[1][0] : &Vl[1][0]) + (wid & 1) * 2048;

    f32x4 oA[8], oB[8];
    #pragma unroll
    for (int i = 0; i < 8; ++i) { oA[i] = (f32x4){0.f, 0.f, 0.f, 0.f}; oB[i] = oA[i]; }
    float laccA = 0.f, laccB = 0.f;

    #pragma unroll
    for (int c = 0; c < 4; ++c)
        __builtin_amdgcn_global_load_lds(
            (const __attribute__((address_space(1))) void*)(gsrc + c * 512 + lane * 8),
            (__attribute__((address_space(3))) void*)(l0 + c * 512), 16, 0, 0);
    __syncthreads();

    for (int jj = 0; jj < ntl; ++jj) {
        const ushort* Kc = &Kl[jj & 1][0];
        const ushort* Vc = &Vl[jj & 1][0];
        if (jj + 1 < ntl) {
            const ushort* src = gsrc + (size_t)(jj + 1) * 4096;
            ushort* dst = ((jj + 1) & 1) ? l1 : l0;
            #pragma unroll
            for (int c = 0; c < 4; ++c)
                __builtin_amdgcn_global_load_lds(
                    (const __attribute__((address_space(1))) void*)(src + c * 512 + lane * 8),
                    (__attribute__((address_space(3))) void*)(dst + c * 512), 16, 0, 0);
        }
        f32x4 s0A = (f32x4){0.f, 0.f, 0.f, 0.f}, s1A = s0A, s0B = s0A, s1B = s0A;
        __builtin_amdgcn_s_setprio(1);
        #pragma unroll
        for (int kc = 0; kc < 4; ++kc) {
            short8 kf0 = *(const short8*)(Kc + ((kc * 2 + 0) * 64 + lane) * 8);
            short8 kf1 = *(const short8*)(Kc + ((kc * 2 + 1) * 64 + lane) * 8);
            s0A = __builtin_amdgcn_mfma_f32_16x16x32_bf16(kf0, qfA[kc], s0A, 0, 0, 0);
            s1A = __builtin_amdgcn_mfma_f32_16x16x32_bf16(kf1, qfA[kc], s1A, 0, 0, 0);
            s0B = __builtin_amdgcn_mfma_f32_16x16x32_bf16(kf0, qfB[kc], s0B, 0, 0, 0);
            s1B = __builtin_amdgcn_mfma_f32_16x16x32_bf16(kf1, qfB[kc], s1B, 0, 0, 0);
        }
        __builtin_amdgcn_s_setprio(0);
        int k0 = (jt0 + jj) * 32;
        float aA[8], aB[8];
        if (k0 + 32 > TT) {   // only the final tile (ks=1, jj=15)
            #pragma unroll
            for (int r = 0; r < 4; ++r) {
                bool v0 = (k0 + 8 * g + r < TT), v1 = (k0 + 8 * g + 4 + r < TT);
                aA[r]     = v0 ? __expf(s0A[r]) : 0.f;
                aA[4 + r] = v1 ? __expf(s1A[r]) : 0.f;
                aB[r]     = v0 ? __expf(s0B[r]) : 0.f;
                aB[4 + r] = v1 ? __expf(s1B[r]) : 0.f;
            }
        } else {
            #pragma unroll
            for (int r = 0; r < 4; ++r) {
                aA[r] = __expf(s0A[r]); aA[4 + r] = __expf(s1A[r]);
                aB[r] = __expf(s0B[r]); aB[4 + r] = __expf(s1B[r]);
            }
        }
        laccA += ((aA[0] + aA[1]) + (aA[2] + aA[3])) + ((aA[4] + aA[5]) + (aA[6] + aA[7]));
        laccB += ((aB[0] + aB[1]) + (aB[2] + aB[3])) + ((aB[4] + aB[5]) + (aB[6] + aB[7]));
        short8 paA, paB;
        #pragma unroll
        for (int e = 0; e < 8; ++e) { paA[e] = (short)f2bf(aA[e]); paB[e] = (short)f2bf(aB[e]); }
        __builtin_amdgcn_s_setprio(1);
        #pragma unroll
        for (int db = 0; db < 8; ++db) {
            short8 vf = *(const short8*)(Vc + (db * 64 + lane) * 8);
            oA[db] = __builtin_amdgcn_mfma_f32_16x16x32_bf16(vf, paA, oA[db], 0, 0, 0);
            oB[db] = __builtin_amdgcn_mfma_f32_16x16x32_bf16(vf, paB, oB[db], 0, 0, 0);
        }
        __builtin_amdgcn_s_setprio(0);
        __syncthreads();   // drains vmcnt (next-tile DMA landed) + WAR on buf
    }

    // epilogue: UNNORMALIZED partial O + partial l (combine happens in proto)
    laccA += __shfl_xor(laccA, 16); laccA += __shfl_xor(laccA, 32);
    laccB += __shfl_xor(laccB, 16); laccB += __shfl_xor(laccB, 32);
    int qrowA = qtA * 16 + r16, qrowB = qtB * 16 + r16;
    size_t base = ((size_t)ks * NSUP + p) * TT;
    if (qrowA < TT) {
        float* po = Opart + (base + qrowA) * DOUT;
        #pragma unroll
        for (int db = 0; db < 8; ++db)
            *(f32x4*)&po[db * 16 + g * 4] = oA[db];
        if (g == 0) lpart[base + qrowA] = laccA;
    }
    if (qrowB < TT) {
        float* po = Opart + (base + qrowB) * DOUT;
        #pragma unroll
        for (int db = 0; db < 8; ++db)
            *(f32x4*)&po[db * 16 + g * 4] = oB[db];
        if (g == 0) lpart[base + qrowB] = laccB;
    }
}

// ---------------- kernel 5: fused proto (split-K combine + shot mean) + logits partials ----------------
__global__ __launch_bounds__(256) void proto_logits_kernel(
        const float* __restrict__ Opart, const float* __restrict__ lpart,
        const float* __restrict__ Vq, float* __restrict__ proto,
        float* __restrict__ partial) {
    int c = blockIdx.y, tid = threadIdx.x;
    int i = blockIdx.x * 256 + tid;     // float4 index within class
    const int n4 = TT * DOUT / 4;       // 33120
    float sum = 0.f;
    if (i < n4) {
        int q = (i * 4) >> 7;           // q row (4 dims are within one row)
        float4 acc = make_float4(0.f, 0.f, 0.f, 0.f);
        #pragma unroll
        for (int s = 0; s < SHOT; ++s) {
            int pr = c * SHOT + s;
            const float4* O0 = (const float4*)(Opart + (size_t)pr * TT * DOUT);
            const float4* O1 = (const float4*)(Opart + ((size_t)NSUP + pr) * TT * DOUT);
            float l = lpart[(size_t)pr * TT + q] + lpart[((size_t)NSUP + pr) * TT + q];
            float inv = 0.2f / l;
            float4 a0 = O0[i], a1 = O1[i];
            acc.x += (a0.x + a1.x) * inv;
            acc.y += (a0.y + a1.y) * inv;
            acc.z += (a0.z + a1.z) * inv;
            acc.w += (a0.w + a1.w) * inv;
        }
        ((float4*)(proto + (size_t)c * TT * DOUT))[i] = acc;
        float4 qv4 = ((const float4*)Vq)[i];
        float dx = qv4.x - acc.x, dy = qv4.y - acc.y;
        float dz = qv4.z - acc.z, dw = qv4.w - acc.w;
        sum = dx * dx + dy * dy + dz * dz + dw * dw;
    }
    for (int off = 32; off >= 1; off >>= 1) sum += __shfl_down(sum, off);
    __shared__ float red[4];
    int w = tid >> 6, lane = tid & 63;
    if (lane == 0) red[w] = sum;
    __syncthreads();
    if (tid == 0) partial[c * NPB + blockIdx.x] = red[0] + red[1] + red[2] + red[3];
}

// ---------------- kernel 6: logits finalize ----------------
__global__ void logits_final_kernel(const float* __restrict__ partial, float* __restrict__ out) {
    int c = threadIdx.x;
    if (c < WAY) {
        float s = 0.f;
        for (int b = 0; b < NPB; ++b) s += partial[c * NPB + b];
        out[c] = -s / (float)TT;
    }
}

// ---------------- kernel 7: argmax + is_true = exp(qv - proto[best]) ----------------
__global__ void istrue_kernel(const float* __restrict__ Vq, const float* __restrict__ proto,
                              float* out) {
    float l0 = out[0];
    int best = 0;
    for (int cc = 1; cc < WAY; ++cc) {
        float lc = out[cc];
        if (lc > l0) { l0 = lc; best = cc; }
    }
    const float* pr = proto + (size_t)best * TT * DOUT;
    int idx = blockIdx.x * 256 + threadIdx.x;
    if (idx < TT * DOUT) out[5 + idx] = expf(Vq[idx] - pr[idx]);
}

extern "C" void kernel_launch(void* const* d_in, const int* in_sizes, int n_in,
                              void* d_out, int out_size, void* d_ws, size_t ws_size,
                              hipStream_t stream) {
    const float* ss  = (const float*)d_in[0];
    const float* qsk = (const float*)d_in[1];
    // d_in[2] = ss_labels (sorted balanced; reduces to a reshape)
    const float* w1 = (const float*)d_in[3];
    const float* b1 = (const float*)d_in[4];
    const float* w2 = (const float*)d_in[5];
    const float* b2 = (const float*)d_in[6];
    const float* kw = (const float*)d_in[7];
    const float* kb = (const float*)d_in[8];
    const float* vw = (const float*)d_in[9];
    const float* vb = (const float*)d_in[10];
    const float* lg = (const float*)d_in[11];
    const float* lb = (const float*)d_in[12];
    float* out = (float*)d_out;

    float* w = (float*)d_ws;
    float* feat = w;                                   // 1196*256 f32
    float* kp1  = feat + 1196 * 256;                   // 1196*128 f32 each
    float* kp2  = kp1 + 1196 * 128;
    float* vp1  = kp2 + 1196 * 128;
    float* vp2  = vp1 + 1196 * 128;
    float* Vq   = vp2 + 1196 * 128;                    // TT*128 f32 (query V)
    float* Opart = Vq + (size_t)TT * DOUT;             // 2*25*TT*128 f32 (split-K partials)
    float* lpart = Opart + (size_t)2 * NSUP * TT * DOUT; // 2*25*TT f32
    float* proto = lpart + (size_t)2 * NSUP * TT;      // 5*TT*128 f32
    float* partial = proto + (size_t)WAY * TT * DOUT;  // WAY*NPB f32
    ushort* Qbf  = (ushort*)(partial + WAY * NPB);     // 72*2048 u16 (frag-order Q)
    ushort* Kbf2 = Qbf + (size_t)72 * 2048;            // 25*33*4096 u16
    ushort* Vbf2 = Kbf2 + (size_t)NSUP * 33 * 4096;    // 25*33*4096 u16
    // total ~48 MB

    hipLaunchKernelGGL(mlp_pe_kernel, dim3(NSEQ * LSEQ), dim3(256), 0, stream,
                       ss, qsk, w1, b1, w2, b2, feat);
    hipLaunchKernelGGL(proj_kernel, dim3(1196 / PROWS), dim3(256), 0, stream,
                       feat, kw, vw, kp1, kp2, vp1, vp2);
    hipLaunchKernelGGL(kv_kernel, dim3(NSEQ * 33), dim3(256), 0, stream,
                       kp1, kp2, vp1, vp2, kb, vb, lg, lb, Qbf, Kbf2, Vbf2, Vq);
    hipLaunchKernelGGL(attn_mfma_kernel, dim3(450), dim3(256), 0, stream,
                       Qbf, Kbf2, Vbf2, Opart, lpart);
    hipLaunchKernelGGL(proto_logits_kernel, dim3(NPB, WAY), dim3(256), 0, stream,
                       Opart, lpart, Vq, proto, partial);
    hipLaunchKernelGGL(logits_final_kernel, dim3(1), dim3(64), 0, stream, partial, out);
    hipLaunchKernelGGL(istrue_kernel, dim3((TT * DOUT + 255) / 256), dim3(256), 0, stream,
                       Vq, proto, out);
}

// Round 16
// 88.399 us; speedup vs baseline: 1.0910x; 1.0910x over previous
//
#include <hip/hip_runtime.h>
#include <hip/hip_bf16.h>
#include <math.h>

#define NSEQ 26
#define NSUP 25
#define LSEQ 46
#define DJ 90
#define H1 180
#define DIN 256
#define TT 1035
#define NKT 34       // key tiles incl. one zero pad tile (34*32 = 1088)
#define DOUT 128
#define WAY 5
#define SHOT 5
#define NPB 130      // proto/logits blocks per class: ceil(33120/256)
#define PROWS 4      // proj rows per block (1196 = 4*299)
#define SQRT_SCALE 0.29730177875068026f   // (1/sqrt(128))^0.5 folded into K (Q and K both)

typedef __attribute__((ext_vector_type(8))) short short8;
typedef __attribute__((ext_vector_type(4))) float f32x4;

__device__ __forceinline__ ushort f2bf(float x) {
    __hip_bfloat16 h = __float2bfloat16(x);
    return *reinterpret_cast<ushort*>(&h);
}

// ---------------- kernel 1: MLP (two relu layers) + positional encoding ----------------
__global__ void mlp_pe_kernel(const float* __restrict__ ss, const float* __restrict__ qsk,
                              const float* __restrict__ w1, const float* __restrict__ b1,
                              const float* __restrict__ w2, const float* __restrict__ b2,
                              float* __restrict__ feat) {
    __shared__ float xs[DJ];
    __shared__ float hs[H1];
    int r = blockIdx.x;
    int seq = r / LSEQ, l = r % LSEQ;
    const float* x = (seq < NSUP) ? (ss + (size_t)(seq * LSEQ + l) * DJ)
                                  : (qsk + (size_t)l * DJ);
    int tid = threadIdx.x;
    if (tid < DJ) xs[tid] = x[tid];
    __syncthreads();
    if (tid < H1) {
        float a = b1[tid];
        for (int k = 0; k < DJ; ++k) a += xs[k] * w1[k * H1 + tid];
        hs[tid] = fmaxf(a, 0.f);
    }
    __syncthreads();
    int d = tid;  // 0..255
    float a = b2[d];
    for (int k = 0; k < H1; ++k) a += hs[k] * w2[k * DIN + d];
    a = fmaxf(a, 0.f);
    int p2 = d & ~1;
    float freq = expf((float)p2 * (-9.210340371976184f / 256.0f));
    float ang = (float)l * freq;
    a += ((d & 1) ? cosf(ang) : sinf(ang)) * 0.1f;
    feat[(size_t)r * DIN + d] = a;
}

// ---------------- kernel 2: half projections, 4 rows/block (weight reuse in-block) ----------------
__global__ __launch_bounds__(256) void proj_kernel(
        const float* __restrict__ feat,
        const float* __restrict__ kw, const float* __restrict__ vw,
        float* __restrict__ kp1, float* __restrict__ kp2,
        float* __restrict__ vp1, float* __restrict__ vp2) {
    __shared__ float fs[PROWS][DIN];
    int r0 = blockIdx.x * PROWS;
    int tid = threadIdx.x;
    int d = tid & 127, h = tid >> 7;   // h=0: kw pair, h=1: vw pair
    #pragma unroll
    for (int rr = 0; rr < PROWS; ++rr)
        fs[rr][tid] = feat[(size_t)(r0 + rr) * DIN + tid];
    __syncthreads();
    const float* W = h ? vw : kw;
    float at[PROWS] = {0.f, 0.f, 0.f, 0.f};
    float ab[PROWS] = {0.f, 0.f, 0.f, 0.f};
    for (int k = 0; k < DIN; ++k) {
        float wt = W[k * DOUT + d];
        float wb = W[(k + DIN) * DOUT + d];
        #pragma unroll
        for (int rr = 0; rr < PROWS; ++rr) {
            float f = fs[rr][k];
            at[rr] += f * wt;
            ab[rr] += f * wb;
        }
    }
    #pragma unroll
    for (int rr = 0; rr < PROWS; ++rr) {
        size_t o = (size_t)(r0 + rr) * DOUT + d;
        if (h == 0) { kp1[o] = at[rr]; kp2[o] = ab[rr]; }
        else        { vp1[o] = at[rr]; vp2[o] = ab[rr]; }
    }
}

// ---------------- kernel 3: tuple gather + bias + LayerNorm ----------------
// Block per (seq, key-tile); kt == 33 is the zero pad tile. K/Q fragment
// stores are 16B per lane. V^T fragments now go through a padded LDS tile
// (float Vt[32][129], <=4-way banks) and are emitted as COALESCED 16B
// chunks (64 lanes -> 1KB contiguous) instead of r15's 8x2B scattered
// stores per lane (the hidden write-coalescing tax).
__global__ __launch_bounds__(256) void kv_kernel(
        const float* __restrict__ kp1, const float* __restrict__ kp2,
        const float* __restrict__ vp1, const float* __restrict__ vp2,
        const float* __restrict__ kb, const float* __restrict__ vb,
        const float* __restrict__ lg, const float* __restrict__ lb,
        ushort* __restrict__ Qbf, ushort* __restrict__ Kbf2,
        ushort* __restrict__ Vbf2, float* __restrict__ Vq) {
    __shared__ float Vt[32][129];
    int s = blockIdx.x / NKT, kt = blockIdx.x % NKT;
    int tid = threadIdx.x, wid = tid >> 6, lane = tid & 63;
    int lgrp = lane >> 4, dl = lane & 15;
    int d0 = dl * 8;
    int kc = d0 >> 5, gk = (d0 >> 3) & 3;

    #pragma unroll
    for (int pp = 0; pp < 2; ++pp) {
        int jq = pp * 16 + wid * 4 + lgrp;      // tuple within tile, 0..31
        int t = kt * 32 + jq;
        bool valid = t < TT;
        float kv8[8], vv8[8];
        #pragma unroll
        for (int e = 0; e < 8; ++e) { kv8[e] = 0.f; vv8[e] = 0.f; }
        if (valid) {
            int i = (int)((91.0f - sqrtf((float)(8281 - 8 * t))) * 0.5f);
            while (i > 0 && t < i * (91 - i) / 2) --i;
            while (i < 44 && t >= (i + 1) * (90 - i) / 2) ++i;
            int j = i + 1 + (t - i * (91 - i) / 2);
            const float* ki = kp1 + (size_t)(s * LSEQ + i) * DOUT + d0;
            const float* kj = kp2 + (size_t)(s * LSEQ + j) * DOUT + d0;
            const float* vi = vp1 + (size_t)(s * LSEQ + i) * DOUT + d0;
            const float* vj = vp2 + (size_t)(s * LSEQ + j) * DOUT + d0;
            #pragma unroll
            for (int e = 0; e < 8; ++e) {
                kv8[e] = ki[e] + kj[e] + kb[d0 + e];
                vv8[e] = vi[e] + vj[e] + vb[d0 + e];
            }
        }
        float sum = 0.f, sq = 0.f;
        #pragma unroll
        for (int e = 0; e < 8; ++e) { sum += kv8[e]; sq += kv8[e] * kv8[e]; }
        sum += __shfl_xor(sum, 1); sq += __shfl_xor(sq, 1);
        sum += __shfl_xor(sum, 2); sq += __shfl_xor(sq, 2);
        sum += __shfl_xor(sum, 4); sq += __shfl_xor(sq, 4);
        sum += __shfl_xor(sum, 8); sq += __shfl_xor(sq, 8);
        float m = sum * (1.f / DOUT);
        float var = sq * (1.f / DOUT) - m * m;
        float rs = rsqrtf(var + 1e-5f);
        short8 kn8;
        #pragma unroll
        for (int e = 0; e < 8; ++e) {
            float kn = valid ? ((kv8[e] - m) * rs * lg[d0 + e] + lb[d0 + e]) * SQRT_SCALE : 0.f;
            kn8[e] = (short)f2bf(kn);
        }
        if (s < NSUP) {
            int pos = (jq & 4) ? (16 + ((jq >> 3) << 2) + (jq & 3))
                               : (((jq >> 3) << 2) + (jq & 3));
            ushort* Ktile = Kbf2 + ((size_t)s * NKT + kt) * 4096;
            *(short8*)(Ktile + (size_t)((kc * 2 + (pos >> 4)) * 64 + gk * 16 + (pos & 15)) * 8) = kn8;
            #pragma unroll
            for (int e = 0; e < 8; ++e) Vt[jq][d0 + e] = vv8[e];   // valid-masked zeros
        } else {
            int qt = t >> 4, r16q = t & 15;
            *(short8*)(Qbf + (size_t)qt * 2048 + (size_t)(kc * 64 + gk * 16 + r16q) * 8) = kn8;
            if (valid) {
                float* vq = Vq + (size_t)t * DOUT + d0;
                #pragma unroll
                for (int e = 0; e < 8; ++e) vq[e] = vv8[e];
            }
        }
    }
    __syncthreads();
    if (s < NSUP) {
        ushort* Vtile = Vbf2 + ((size_t)s * NKT + kt) * 4096;
        #pragma unroll
        for (int c = tid; c < 512; c += 256) {
            int r16v = c & 15, gv = (c >> 4) & 3, db = c >> 6;
            short8 pk;
            #pragma unroll
            for (int ev = 0; ev < 8; ++ev)
                pk[ev] = (short)f2bf(Vt[gv * 8 + ev][db * 16 + r16v]);
            *(short8*)(Vtile + (size_t)c * 8) = pk;    // coalesced: wave = 1KB run
        }
    }
}

// ---------------- kernel 4: MFMA flash attention, KVBLK=64 chunks ----------------
// 425 blocks (17 qg x 25 pairs), 4 waves x 1 q-tile. Per chunk: 2 key-tiles
// (32KB K+V) staged via global_load_lds; 17 barriers instead of 33 (each
// __syncthreads costs a full vmcnt drain). Zero pad tile kt=33 is masked by
// the key<TT exp-mask. P in-register (permuted-K), fixed-max softmax,
// normalized direct O write (no split-K round-trip).
__global__ __launch_bounds__(256) void attn_mfma_kernel(
        const ushort* __restrict__ Qbf, const ushort* __restrict__ Kbf2,
        const ushort* __restrict__ Vbf2, float* __restrict__ Obuf) {
    __shared__ __align__(16) ushort Kl[2][8192];
    __shared__ __align__(16) ushort Vl[2][8192];

    // bijective XCD-chunk swizzle (nwg=425)
    const int nwg = 17 * NSUP;
    int orig = blockIdx.x;
    int cq = nwg >> 3, cr = nwg & 7;           // 53, 1
    int xcd = orig & 7, sub = orig >> 3;
    int wg = (xcd < cr ? xcd * (cq + 1) : cr * (cq + 1) + (xcd - cr) * cq) + sub;
    int p = wg / 17;

    int tid = threadIdx.x, wid = tid >> 6, lane = tid & 63;
    int g = lane >> 4, r16 = lane & 15;
    int qt = (wg % 17) * 4 + wid;              // 0..67 (66,67 masked)

    const short8 z8 = (short8){0, 0, 0, 0, 0, 0, 0, 0};
    short8 qf[4];
    {
        const ushort* Qb = Qbf + (size_t)qt * 2048;
        bool ok = qt < 66;
        #pragma unroll
        for (int kc = 0; kc < 4; ++kc)
            qf[kc] = ok ? *(const short8*)(Qb + (kc * 64 + lane) * 8) : z8;
    }

    // staging split: wave0 K[0:8KB), wave1 K[8KB:16KB), wave2/3 same for V
    const ushort* gsrc = ((wid < 2) ? Kbf2 : Vbf2) + (size_t)p * NKT * 4096 + (size_t)(wid & 1) * 4096;
    ushort* l0 = ((wid < 2) ? &Kl[0][0] : &Vl[0][0]) + (wid & 1) * 4096;
    ushort* l1 = ((wid < 2) ? &Kl[1][0] : &Vl[1][0]) + (wid & 1) * 4096;

    f32x4 o[8];
    #pragma unroll
    for (int i = 0; i < 8; ++i) o[i] = (f32x4){0.f, 0.f, 0.f, 0.f};
    float lacc = 0.f;

    #pragma unroll
    for (int c = 0; c < 8; ++c)
        __builtin_amdgcn_global_load_lds(
            (const __attribute__((address_space(1))) void*)(gsrc + c * 512 + lane * 8),
            (__attribute__((address_space(3))) void*)(l0 + c * 512), 16, 0, 0);
    __syncthreads();

    for (int cc = 0; cc < 17; ++cc) {
        const ushort* Kc = &Kl[cc & 1][0];
        const ushort* Vc = &Vl[cc & 1][0];
        if (cc + 1 < 17) {   // DMA next chunk into the other buffer
            const ushort* src = gsrc + (size_t)(cc + 1) * 8192;
            ushort* dst = ((cc + 1) & 1) ? l1 : l0;
            #pragma unroll
            for (int c = 0; c < 8; ++c)
                __builtin_amdgcn_global_load_lds(
                    (const __attribute__((address_space(1))) void*)(src + c * 512 + lane * 8),
                    (__attribute__((address_space(3))) void*)(dst + c * 512), 16, 0, 0);
        }
        #pragma unroll
        for (int st = 0; st < 2; ++st) {
            const ushort* Kb = Kc + st * 4096;
            const ushort* Vb = Vc + st * 4096;
            int k0 = cc * 64 + st * 32;
            f32x4 s0 = (f32x4){0.f, 0.f, 0.f, 0.f}, s1 = s0;
            __builtin_amdgcn_s_setprio(1);
            #pragma unroll
            for (int kc = 0; kc < 4; ++kc) {
                short8 kf0 = *(const short8*)(Kb + ((kc * 2 + 0) * 64 + lane) * 8);
                short8 kf1 = *(const short8*)(Kb + ((kc * 2 + 1) * 64 + lane) * 8);
                s0 = __builtin_amdgcn_mfma_f32_16x16x32_bf16(kf0, qf[kc], s0, 0, 0, 0);
                s1 = __builtin_amdgcn_mfma_f32_16x16x32_bf16(kf1, qf[kc], s1, 0, 0, 0);
            }
            __builtin_amdgcn_s_setprio(0);
            float a[8];
            if (k0 + 32 > TT) {   // final tiles incl. zero pad tile
                #pragma unroll
                for (int r = 0; r < 4; ++r) {
                    a[r]     = (k0 + 8 * g + r < TT)     ? __expf(s0[r]) : 0.f;
                    a[4 + r] = (k0 + 8 * g + 4 + r < TT) ? __expf(s1[r]) : 0.f;
                }
            } else {
                #pragma unroll
                for (int r = 0; r < 4; ++r) { a[r] = __expf(s0[r]); a[4 + r] = __expf(s1[r]); }
            }
            lacc += ((a[0] + a[1]) + (a[2] + a[3])) + ((a[4] + a[5]) + (a[6] + a[7]));
            short8 pa;
            #pragma unroll
            for (int e = 0; e < 8; ++e) pa[e] = (short)f2bf(a[e]);
            __builtin_amdgcn_s_setprio(1);
            #pragma unroll
            for (int db = 0; db < 8; ++db) {
                short8 vf = *(const short8*)(Vb + (db * 64 + lane) * 8);
                o[db] = __builtin_amdgcn_mfma_f32_16x16x32_bf16(vf, pa, o[db], 0, 0, 0);
            }
            __builtin_amdgcn_s_setprio(0);
        }
        __syncthreads();   // drains vmcnt (next-chunk DMA landed) + WAR on buf
    }

    lacc += __shfl_xor(lacc, 16);
    lacc += __shfl_xor(lacc, 32);
    float invL = 1.f / lacc;
    int qrow = qt * 16 + r16;
    if (qrow < TT) {
        float* po = Obuf + ((size_t)p * TT + qrow) * DOUT;
        #pragma unroll
        for (int db = 0; db < 8; ++db) {
            float4 w4 = make_float4(o[db][0] * invL, o[db][1] * invL,
                                    o[db][2] * invL, o[db][3] * invL);
            *(float4*)&po[db * 16 + g * 4] = w4;
        }
    }
}

// ---------------- kernel 5: fused proto (shot mean) + logits partials ----------------
__global__ __launch_bounds__(256) void proto_logits_kernel(
        const float* __restrict__ Obuf, const float* __restrict__ Vq,
        float* __restrict__ proto, float* __restrict__ partial) {
    int c = blockIdx.y, tid = threadIdx.x;
    int i = blockIdx.x * 256 + tid;     // float4 index within class
    const int n4 = TT * DOUT / 4;       // 33120
    float sum = 0.f;
    if (i < n4) {
        float4 acc = make_float4(0.f, 0.f, 0.f, 0.f);
        #pragma unroll
        for (int s = 0; s < SHOT; ++s) {
            const float4* O = (const float4*)(Obuf + (size_t)(c * SHOT + s) * TT * DOUT);
            float4 a0 = O[i];
            acc.x += a0.x; acc.y += a0.y; acc.z += a0.z; acc.w += a0.w;
        }
        acc.x *= 0.2f; acc.y *= 0.2f; acc.z *= 0.2f; acc.w *= 0.2f;
        ((float4*)(proto + (size_t)c * TT * DOUT))[i] = acc;
        float4 qv4 = ((const float4*)Vq)[i];
        float dx = qv4.x - acc.x, dy = qv4.y - acc.y;
        float dz = qv4.z - acc.z, dw = qv4.w - acc.w;
        sum = dx * dx + dy * dy + dz * dz + dw * dw;
    }
    for (int off = 32; off >= 1; off >>= 1) sum += __shfl_down(sum, off);
    __shared__ float red[4];
    int w = tid >> 6, lane = tid & 63;
    if (lane == 0) red[w] = sum;
    __syncthreads();
    if (tid == 0) partial[c * NPB + blockIdx.x] = red[0] + red[1] + red[2] + red[3];
}

// ---------------- kernel 6: fused logits finalize + argmax + is_true ----------------
// Every block redundantly reduces the 5x130 partials (broadcast L2 reads),
// computes logits + argmax locally; block 0 writes out[0..4].
__global__ __launch_bounds__(256) void istrue_kernel(
        const float* __restrict__ Vq, const float* __restrict__ proto,
        const float* __restrict__ partial, float* out) {
    __shared__ float lgv[WAY];
    int tid = threadIdx.x, wv = tid >> 6, lane = tid & 63;
    for (int c = wv; c < WAY; c += 4) {
        float s = 0.f;
        for (int b = lane; b < NPB; b += 64) s += partial[c * NPB + b];
        for (int off = 32; off >= 1; off >>= 1) s += __shfl_down(s, off);
        if (lane == 0) lgv[c] = -s / (float)TT;
    }
    __syncthreads();
    float l0 = lgv[0];
    int best = 0;
    #pragma unroll
    for (int cc = 1; cc < WAY; ++cc) {
        float lc = lgv[cc];
        if (lc > l0) { l0 = lc; best = cc; }
    }
    if (blockIdx.x == 0 && tid < WAY) out[tid] = lgv[tid];
    int idx = blockIdx.x * 256 + tid;
    if (idx < TT * DOUT)
        out[5 + idx] = expf(Vq[idx] - proto[(size_t)best * TT * DOUT + idx]);
}

extern "C" void kernel_launch(void* const* d_in, const int* in_sizes, int n_in,
                              void* d_out, int out_size, void* d_ws, size_t ws_size,
                              hipStream_t stream) {
    const float* ss  = (const float*)d_in[0];
    const float* qsk = (const float*)d_in[1];
    // d_in[2] = ss_labels (sorted balanced; reduces to a reshape)
    const float* w1 = (const float*)d_in[3];
    const float* b1 = (const float*)d_in[4];
    const float* w2 = (const float*)d_in[5];
    const float* b2 = (const float*)d_in[6];
    const float* kw = (const float*)d_in[7];
    const float* kb = (const float*)d_in[8];
    const float* vw = (const float*)d_in[9];
    const float* vb = (const float*)d_in[10];
    const float* lg = (const float*)d_in[11];
    const float* lb = (const float*)d_in[12];
    float* out = (float*)d_out;

    float* w = (float*)d_ws;
    float* feat = w;                                   // 1196*256 f32
    float* kp1  = feat + 1196 * 256;                   // 1196*128 f32 each
    float* kp2  = kp1 + 1196 * 128;
    float* vp1  = kp2 + 1196 * 128;
    float* vp2  = vp1 + 1196 * 128;
    float* Vq   = vp2 + 1196 * 128;                    // TT*128 f32 (query V)
    float* Obuf = Vq + (size_t)TT * DOUT;              // 25*TT*128 f32 (normalized)
    float* proto = Obuf + (size_t)NSUP * TT * DOUT;    // 5*TT*128 f32
    float* partial = proto + (size_t)WAY * TT * DOUT;  // WAY*NPB f32
    ushort* Qbf  = (ushort*)(partial + WAY * NPB);     // 72*2048 u16 (frag-order Q)
    ushort* Kbf2 = Qbf + (size_t)72 * 2048;            // 25*34*4096 u16 (incl. pad tile)
    ushort* Vbf2 = Kbf2 + (size_t)NSUP * NKT * 4096;   // 25*34*4096 u16
    // total ~35 MB

    hipLaunchKernelGGL(mlp_pe_kernel, dim3(NSEQ * LSEQ), dim3(256), 0, stream,
                       ss, qsk, w1, b1, w2, b2, feat);
    hipLaunchKernelGGL(proj_kernel, dim3(1196 / PROWS), dim3(256), 0, stream,
                       feat, kw, vw, kp1, kp2, vp1, vp2);
    hipLaunchKernelGGL(kv_kernel, dim3(NSEQ * NKT), dim3(256), 0, stream,
                       kp1, kp2, vp1, vp2, kb, vb, lg, lb, Qbf, Kbf2, Vbf2, Vq);
    hipLaunchKernelGGL(attn_mfma_kernel, dim3(17 * NSUP), dim3(256), 0, stream,
                       Qbf, Kbf2, Vbf2, Obuf);
    hipLaunchKernelGGL(proto_logits_kernel, dim3(NPB, WAY), dim3(256), 0, stream,
                       Obuf, Vq, proto, partial);
    hipLaunchKernelGGL(istrue_kernel, dim3((TT * DOUT + 255) / 256), dim3(256), 0, stream,
                       Vq, proto, partial, out);
}

// Round 17
// 84.883 us; speedup vs baseline: 1.1362x; 1.0414x over previous
//
#include <hip/hip_runtime.h>
#include <hip/hip_bf16.h>
#include <math.h>

#define NSEQ 26
#define NSUP 25
#define LSEQ 46
#define DJ 90
#define H1 180
#define DIN 256
#define TT 1035
#define NKT 34       // key tiles incl. one zero pad tile (34*32 = 1088)
#define DOUT 128
#define WAY 5
#define SHOT 5
#define NPB 130      // proto/logits blocks per class: ceil(33120/256)
#define PROWS 4      // rows per featproj block (1196 = 4*299)
#define SQRT_SCALE 0.29730177875068026f   // (1/sqrt(128))^0.5 folded into K (Q and K both)

typedef __attribute__((ext_vector_type(8))) short short8;
typedef __attribute__((ext_vector_type(4))) float f32x4;

__device__ __forceinline__ ushort f2bf(float x) {
    __hip_bfloat16 h = __float2bfloat16(x);
    return *reinterpret_cast<ushort*>(&h);
}

// ---------------- kernel 1: fused MLP + PE + K/V half-projections ----------------
// 299 blocks x 4 rows. Row r's projection depends only on feat row r, so the
// whole front-end chain runs through LDS: xs -> (w1,relu) -> hs -> (w2,relu,PE)
// -> fs -> (kw|vw) -> kp/vp. One dispatch instead of two; no feat round-trip;
// MLP weights get the same 4x in-block reuse as the projection weights
// (total weight traffic 450 -> 227 MB).
__global__ __launch_bounds__(256) void featproj_kernel(
        const float* __restrict__ ss, const float* __restrict__ qsk,
        const float* __restrict__ w1, const float* __restrict__ b1,
        const float* __restrict__ w2, const float* __restrict__ b2,
        const float* __restrict__ kw, const float* __restrict__ vw,
        float* __restrict__ kp1, float* __restrict__ kp2,
        float* __restrict__ vp1, float* __restrict__ vp2) {
    __shared__ float xs[PROWS][DJ];
    __shared__ float hs[PROWS][H1];
    __shared__ float fs[PROWS][DIN];
    int r0 = blockIdx.x * PROWS;
    int tid = threadIdx.x;

    for (int idx = tid; idx < PROWS * DJ; idx += 256) {
        int rr = idx / DJ, e = idx % DJ;
        int r = r0 + rr, seq = r / LSEQ, l = r % LSEQ;
        const float* x = (seq < NSUP) ? (ss + (size_t)(seq * LSEQ + l) * DJ)
                                      : (qsk + (size_t)l * DJ);
        xs[rr][e] = x[e];
    }
    __syncthreads();

    if (tid < H1) {   // layer 1: 180 outputs per row, w1 read once per k
        float acc[PROWS];
        #pragma unroll
        for (int rr = 0; rr < PROWS; ++rr) acc[rr] = b1[tid];
        for (int k = 0; k < DJ; ++k) {
            float wv = w1[k * H1 + tid];
            #pragma unroll
            for (int rr = 0; rr < PROWS; ++rr) acc[rr] += xs[rr][k] * wv;
        }
        #pragma unroll
        for (int rr = 0; rr < PROWS; ++rr) hs[rr][tid] = fmaxf(acc[rr], 0.f);
    }
    __syncthreads();

    {   // layer 2 + relu + positional encoding
        float acc[PROWS];
        #pragma unroll
        for (int rr = 0; rr < PROWS; ++rr) acc[rr] = b2[tid];
        for (int k = 0; k < H1; ++k) {
            float wv = w2[k * DIN + tid];
            #pragma unroll
            for (int rr = 0; rr < PROWS; ++rr) acc[rr] += hs[rr][k] * wv;
        }
        int p2 = tid & ~1;
        float freq = expf((float)p2 * (-9.210340371976184f / 256.0f));
        #pragma unroll
        for (int rr = 0; rr < PROWS; ++rr) {
            int l = (r0 + rr) % LSEQ;
            float ang = (float)l * freq;
            fs[rr][tid] = fmaxf(acc[rr], 0.f) + ((tid & 1) ? cosf(ang) : sinf(ang)) * 0.1f;
        }
    }
    __syncthreads();

    // projections: h=0 -> kw halves, h=1 -> vw halves (identical to old proj)
    int d = tid & 127, h = tid >> 7;
    const float* W = h ? vw : kw;
    float at[PROWS] = {0.f, 0.f, 0.f, 0.f};
    float ab[PROWS] = {0.f, 0.f, 0.f, 0.f};
    for (int k = 0; k < DIN; ++k) {
        float wt = W[k * DOUT + d];
        float wb = W[(k + DIN) * DOUT + d];
        #pragma unroll
        for (int rr = 0; rr < PROWS; ++rr) {
            float f = fs[rr][k];
            at[rr] += f * wt;
            ab[rr] += f * wb;
        }
    }
    #pragma unroll
    for (int rr = 0; rr < PROWS; ++rr) {
        size_t o = (size_t)(r0 + rr) * DOUT + d;
        if (h == 0) { kp1[o] = at[rr]; kp2[o] = ab[rr]; }
        else        { vp1[o] = at[rr]; vp2[o] = ab[rr]; }
    }
}

// ---------------- kernel 2: tuple gather + bias + LayerNorm ----------------
// Block per (seq, key-tile); kt == 33 is the zero pad tile. K/Q fragment
// stores are 16B per lane. V^T fragments go through a padded LDS tile and
// are emitted as COALESCED 16B chunks (64 lanes -> 1KB contiguous).
__global__ __launch_bounds__(256) void kv_kernel(
        const float* __restrict__ kp1, const float* __restrict__ kp2,
        const float* __restrict__ vp1, const float* __restrict__ vp2,
        const float* __restrict__ kb, const float* __restrict__ vb,
        const float* __restrict__ lg, const float* __restrict__ lb,
        ushort* __restrict__ Qbf, ushort* __restrict__ Kbf2,
        ushort* __restrict__ Vbf2, float* __restrict__ Vq) {
    __shared__ float Vt[32][129];
    int s = blockIdx.x / NKT, kt = blockIdx.x % NKT;
    int tid = threadIdx.x, wid = tid >> 6, lane = tid & 63;
    int lgrp = lane >> 4, dl = lane & 15;
    int d0 = dl * 8;
    int kc = d0 >> 5, gk = (d0 >> 3) & 3;

    #pragma unroll
    for (int pp = 0; pp < 2; ++pp) {
        int jq = pp * 16 + wid * 4 + lgrp;      // tuple within tile, 0..31
        int t = kt * 32 + jq;
        bool valid = t < TT;
        float kv8[8], vv8[8];
        #pragma unroll
        for (int e = 0; e < 8; ++e) { kv8[e] = 0.f; vv8[e] = 0.f; }
        if (valid) {
            int i = (int)((91.0f - sqrtf((float)(8281 - 8 * t))) * 0.5f);
            while (i > 0 && t < i * (91 - i) / 2) --i;
            while (i < 44 && t >= (i + 1) * (90 - i) / 2) ++i;
            int j = i + 1 + (t - i * (91 - i) / 2);
            const float* ki = kp1 + (size_t)(s * LSEQ + i) * DOUT + d0;
            const float* kj = kp2 + (size_t)(s * LSEQ + j) * DOUT + d0;
            const float* vi = vp1 + (size_t)(s * LSEQ + i) * DOUT + d0;
            const float* vj = vp2 + (size_t)(s * LSEQ + j) * DOUT + d0;
            #pragma unroll
            for (int e = 0; e < 8; ++e) {
                kv8[e] = ki[e] + kj[e] + kb[d0 + e];
                vv8[e] = vi[e] + vj[e] + vb[d0 + e];
            }
        }
        float sum = 0.f, sq = 0.f;
        #pragma unroll
        for (int e = 0; e < 8; ++e) { sum += kv8[e]; sq += kv8[e] * kv8[e]; }
        sum += __shfl_xor(sum, 1); sq += __shfl_xor(sq, 1);
        sum += __shfl_xor(sum, 2); sq += __shfl_xor(sq, 2);
        sum += __shfl_xor(sum, 4); sq += __shfl_xor(sq, 4);
        sum += __shfl_xor(sum, 8); sq += __shfl_xor(sq, 8);
        float m = sum * (1.f / DOUT);
        float var = sq * (1.f / DOUT) - m * m;
        float rs = rsqrtf(var + 1e-5f);
        short8 kn8;
        #pragma unroll
        for (int e = 0; e < 8; ++e) {
            float kn = valid ? ((kv8[e] - m) * rs * lg[d0 + e] + lb[d0 + e]) * SQRT_SCALE : 0.f;
            kn8[e] = (short)f2bf(kn);
        }
        if (s < NSUP) {
            int pos = (jq & 4) ? (16 + ((jq >> 3) << 2) + (jq & 3))
                               : (((jq >> 3) << 2) + (jq & 3));
            ushort* Ktile = Kbf2 + ((size_t)s * NKT + kt) * 4096;
            *(short8*)(Ktile + (size_t)((kc * 2 + (pos >> 4)) * 64 + gk * 16 + (pos & 15)) * 8) = kn8;
            #pragma unroll
            for (int e = 0; e < 8; ++e) Vt[jq][d0 + e] = vv8[e];   // valid-masked zeros
        } else {
            int qt = t >> 4, r16q = t & 15;
            *(short8*)(Qbf + (size_t)qt * 2048 + (size_t)(kc * 64 + gk * 16 + r16q) * 8) = kn8;
            if (valid) {
                float* vq = Vq + (size_t)t * DOUT + d0;
                #pragma unroll
                for (int e = 0; e < 8; ++e) vq[e] = vv8[e];
            }
        }
    }
    __syncthreads();
    if (s < NSUP) {
        ushort* Vtile = Vbf2 + ((size_t)s * NKT + kt) * 4096;
        #pragma unroll
        for (int c = tid; c < 512; c += 256) {
            int r16v = c & 15, gv = (c >> 4) & 3, db = c >> 6;
            short8 pk;
            #pragma unroll
            for (int ev = 0; ev < 8; ++ev)
                pk[ev] = (short)f2bf(Vt[gv * 8 + ev][db * 16 + r16v]);
            *(short8*)(Vtile + (size_t)c * 8) = pk;    // coalesced: wave = 1KB run
        }
    }
}

// ---------------- kernel 3: MFMA flash attention, KVBLK=64 chunks ----------------
__global__ __launch_bounds__(256) void attn_mfma_kernel(
        const ushort* __restrict__ Qbf, const ushort* __restrict__ Kbf2,
        const ushort* __restrict__ Vbf2, float* __restrict__ Obuf) {
    __shared__ __align__(16) ushort Kl[2][8192];
    __shared__ __align__(16) ushort Vl[2][8192];

    // bijective XCD-chunk swizzle (nwg=425)
    const int nwg = 17 * NSUP;
    int orig = blockIdx.x;
    int cq = nwg >> 3, cr = nwg & 7;           // 53, 1
    int xcd = orig & 7, sub = orig >> 3;
    int wg = (xcd < cr ? xcd * (cq + 1) : cr * (cq + 1) + (xcd - cr) * cq) + sub;
    int p = wg / 17;

    int tid = threadIdx.x, wid = tid >> 6, lane = tid & 63;
    int g = lane >> 4, r16 = lane & 15;
    int qt = (wg % 17) * 4 + wid;              // 0..67 (66,67 masked)

    const short8 z8 = (short8){0, 0, 0, 0, 0, 0, 0, 0};
    short8 qf[4];
    {
        const ushort* Qb = Qbf + (size_t)qt * 2048;
        bool ok = qt < 66;
        #pragma unroll
        for (int kc = 0; kc < 4; ++kc)
            qf[kc] = ok ? *(const short8*)(Qb + (kc * 64 + lane) * 8) : z8;
    }

    // staging split: wave0 K[0:8KB), wave1 K[8KB:16KB), wave2/3 same for V
    const ushort* gsrc = ((wid < 2) ? Kbf2 : Vbf2) + (size_t)p * NKT * 4096 + (size_t)(wid & 1) * 4096;
    ushort* l0 = ((wid < 2) ? &Kl[0][0] : &Vl[0][0]) + (wid & 1) * 4096;
    ushort* l1 = ((wid < 2) ? &Kl[1][0] : &Vl[1][0]) + (wid & 1) * 4096;

    f32x4 o[8];
    #pragma unroll
    for (int i = 0; i < 8; ++i) o[i] = (f32x4){0.f, 0.f, 0.f, 0.f};
    float lacc = 0.f;

    #pragma unroll
    for (int c = 0; c < 8; ++c)
        __builtin_amdgcn_global_load_lds(
            (const __attribute__((address_space(1))) void*)(gsrc + c * 512 + lane * 8),
            (__attribute__((address_space(3))) void*)(l0 + c * 512), 16, 0, 0);
    __syncthreads();

    for (int cc = 0; cc < 17; ++cc) {
        const ushort* Kc = &Kl[cc & 1][0];
        const ushort* Vc = &Vl[cc & 1][0];
        if (cc + 1 < 17) {   // DMA next chunk into the other buffer
            const ushort* src = gsrc + (size_t)(cc + 1) * 8192;
            ushort* dst = ((cc + 1) & 1) ? l1 : l0;
            #pragma unroll
            for (int c = 0; c < 8; ++c)
                __builtin_amdgcn_global_load_lds(
                    (const __attribute__((address_space(1))) void*)(src + c * 512 + lane * 8),
                    (__attribute__((address_space(3))) void*)(dst + c * 512), 16, 0, 0);
        }
        #pragma unroll
        for (int st = 0; st < 2; ++st) {
            const ushort* Kb = Kc + st * 4096;
            const ushort* Vb = Vc + st * 4096;
            int k0 = cc * 64 + st * 32;
            f32x4 s0 = (f32x4){0.f, 0.f, 0.f, 0.f}, s1 = s0;
            __builtin_amdgcn_s_setprio(1);
            #pragma unroll
            for (int kc = 0; kc < 4; ++kc) {
                short8 kf0 = *(const short8*)(Kb + ((kc * 2 + 0) * 64 + lane) * 8);
                short8 kf1 = *(const short8*)(Kb + ((kc * 2 + 1) * 64 + lane) * 8);
                s0 = __builtin_amdgcn_mfma_f32_16x16x32_bf16(kf0, qf[kc], s0, 0, 0, 0);
                s1 = __builtin_amdgcn_mfma_f32_16x16x32_bf16(kf1, qf[kc], s1, 0, 0, 0);
            }
            __builtin_amdgcn_s_setprio(0);
            float a[8];
            if (k0 + 32 > TT) {   // final tiles incl. zero pad tile
                #pragma unroll
                for (int r = 0; r < 4; ++r) {
                    a[r]     = (k0 + 8 * g + r < TT)     ? __expf(s0[r]) : 0.f;
                    a[4 + r] = (k0 + 8 * g + 4 + r < TT) ? __expf(s1[r]) : 0.f;
                }
            } else {
                #pragma unroll
                for (int r = 0; r < 4; ++r) { a[r] = __expf(s0[r]); a[4 + r] = __expf(s1[r]); }
            }
            lacc += ((a[0] + a[1]) + (a[2] + a[3])) + ((a[4] + a[5]) + (a[6] + a[7]));
            short8 pa;
            #pragma unroll
            for (int e = 0; e < 8; ++e) pa[e] = (short)f2bf(a[e]);
            __builtin_amdgcn_s_setprio(1);
            #pragma unroll
            for (int db = 0; db < 8; ++db) {
                short8 vf = *(const short8*)(Vb + (db * 64 + lane) * 8);
                o[db] = __builtin_amdgcn_mfma_f32_16x16x32_bf16(vf, pa, o[db], 0, 0, 0);
            }
            __builtin_amdgcn_s_setprio(0);
        }
        __syncthreads();   // drains vmcnt (next-chunk DMA landed) + WAR on buf
    }

    lacc += __shfl_xor(lacc, 16);
    lacc += __shfl_xor(lacc, 32);
    float invL = 1.f / lacc;
    int qrow = qt * 16 + r16;
    if (qrow < TT) {
        float* po = Obuf + ((size_t)p * TT + qrow) * DOUT;
        #pragma unroll
        for (int db = 0; db < 8; ++db) {
            float4 w4 = make_float4(o[db][0] * invL, o[db][1] * invL,
                                    o[db][2] * invL, o[db][3] * invL);
            *(float4*)&po[db * 16 + g * 4] = w4;
        }
    }
}

// ---------------- kernel 4: fused proto (shot mean) + logits partials ----------------
__global__ __launch_bounds__(256) void proto_logits_kernel(
        const float* __restrict__ Obuf, const float* __restrict__ Vq,
        float* __restrict__ proto, float* __restrict__ partial) {
    int c = blockIdx.y, tid = threadIdx.x;
    int i = blockIdx.x * 256 + tid;     // float4 index within class
    const int n4 = TT * DOUT / 4;       // 33120
    float sum = 0.f;
    if (i < n4) {
        float4 acc = make_float4(0.f, 0.f, 0.f, 0.f);
        #pragma unroll
        for (int s = 0; s < SHOT; ++s) {
            const float4* O = (const float4*)(Obuf + (size_t)(c * SHOT + s) * TT * DOUT);
            float4 a0 = O[i];
            acc.x += a0.x; acc.y += a0.y; acc.z += a0.z; acc.w += a0.w;
        }
        acc.x *= 0.2f; acc.y *= 0.2f; acc.z *= 0.2f; acc.w *= 0.2f;
        ((float4*)(proto + (size_t)c * TT * DOUT))[i] = acc;
        float4 qv4 = ((const float4*)Vq)[i];
        float dx = qv4.x - acc.x, dy = qv4.y - acc.y;
        float dz = qv4.z - acc.z, dw = qv4.w - acc.w;
        sum = dx * dx + dy * dy + dz * dz + dw * dw;
    }
    for (int off = 32; off >= 1; off >>= 1) sum += __shfl_down(sum, off);
    __shared__ float red[4];
    int w = tid >> 6, lane = tid & 63;
    if (lane == 0) red[w] = sum;
    __syncthreads();
    if (tid == 0) partial[c * NPB + blockIdx.x] = red[0] + red[1] + red[2] + red[3];
}

// ---------------- kernel 5: fused logits finalize + argmax + is_true ----------------
__global__ __launch_bounds__(256) void istrue_kernel(
        const float* __restrict__ Vq, const float* __restrict__ proto,
        const float* __restrict__ partial, float* out) {
    __shared__ float lgv[WAY];
    int tid = threadIdx.x, wv = tid >> 6, lane = tid & 63;
    for (int c = wv; c < WAY; c += 4) {
        float s = 0.f;
        for (int b = lane; b < NPB; b += 64) s += partial[c * NPB + b];
        for (int off = 32; off >= 1; off >>= 1) s += __shfl_down(s, off);
        if (lane == 0) lgv[c] = -s / (float)TT;
    }
    __syncthreads();
    float l0 = lgv[0];
    int best = 0;
    #pragma unroll
    for (int cc = 1; cc < WAY; ++cc) {
        float lc = lgv[cc];
        if (lc > l0) { l0 = lc; best = cc; }
    }
    if (blockIdx.x == 0 && tid < WAY) out[tid] = lgv[tid];
    int idx = blockIdx.x * 256 + tid;
    if (idx < TT * DOUT)
        out[5 + idx] = expf(Vq[idx] - proto[(size_t)best * TT * DOUT + idx]);
}

extern "C" void kernel_launch(void* const* d_in, const int* in_sizes, int n_in,
                              void* d_out, int out_size, void* d_ws, size_t ws_size,
                              hipStream_t stream) {
    const float* ss  = (const float*)d_in[0];
    const float* qsk = (const float*)d_in[1];
    // d_in[2] = ss_labels (sorted balanced; reduces to a reshape)
    const float* w1 = (const float*)d_in[3];
    const float* b1 = (const float*)d_in[4];
    const float* w2 = (const float*)d_in[5];
    const float* b2 = (const float*)d_in[6];
    const float* kw = (const float*)d_in[7];
    const float* kb = (const float*)d_in[8];
    const float* vw = (const float*)d_in[9];
    const float* vb = (const float*)d_in[10];
    const float* lg = (const float*)d_in[11];
    const float* lb = (const float*)d_in[12];
    float* out = (float*)d_out;

    float* w = (float*)d_ws;
    float* kp1  = w;                                   // 1196*128 f32 each
    float* kp2  = kp1 + 1196 * 128;
    float* vp1  = kp2 + 1196 * 128;
    float* vp2  = vp1 + 1196 * 128;
    float* Vq   = vp2 + 1196 * 128;                    // TT*128 f32 (query V)
    float* Obuf = Vq + (size_t)TT * DOUT;              // 25*TT*128 f32 (normalized)
    float* proto = Obuf + (size_t)NSUP * TT * DOUT;    // 5*TT*128 f32
    float* partial = proto + (size_t)WAY * TT * DOUT;  // WAY*NPB f32
    ushort* Qbf  = (ushort*)(partial + WAY * NPB);     // 72*2048 u16 (frag-order Q)
    ushort* Kbf2 = Qbf + (size_t)72 * 2048;            // 25*34*4096 u16 (incl. pad tile)
    ushort* Vbf2 = Kbf2 + (size_t)NSUP * NKT * 4096;   // 25*34*4096 u16
    // total ~34 MB

    hipLaunchKernelGGL(featproj_kernel, dim3(1196 / PROWS), dim3(256), 0, stream,
                       ss, qsk, w1, b1, w2, b2, kw, vw, kp1, kp2, vp1, vp2);
    hipLaunchKernelGGL(kv_kernel, dim3(NSEQ * NKT), dim3(256), 0, stream,
                       kp1, kp2, vp1, vp2, kb, vb, lg, lb, Qbf, Kbf2, Vbf2, Vq);
    hipLaunchKernelGGL(attn_mfma_kernel, dim3(17 * NSUP), dim3(256), 0, stream,
                       Qbf, Kbf2, Vbf2, Obuf);
    hipLaunchKernelGGL(proto_logits_kernel, dim3(NPB, WAY), dim3(256), 0, stream,
                       Obuf, Vq, proto, partial);
    hipLaunchKernelGGL(istrue_kernel, dim3((TT * DOUT + 255) / 256), dim3(256), 0, stream,
                       Vq, proto, partial, out);
}